// Round 4
// baseline (187.498 us; speedup 1.0000x reference)
//
#include <hip/hip_runtime.h>
#include <hip/hip_bf16.h>

#define B 64
#define T 1024
#define C 768
#define TSPLIT 32           // t-chunks for partial reductions
#define TCHUNK (T / TSPLIT) // 32

// ---------------- ws layout (float offsets) ----------------
#define OFF_MSUM   64
#define OFF_ASUM   (OFF_MSUM + B*TSPLIT*C)
#define OFF_CNT    (OFF_ASUM + B*TSPLIT*C)
#define OFF_QSAL   (OFF_CNT + B*TSPLIT)
#define OFF_Q      (OFF_QSAL + B*C)
#define OFF_QK     (OFF_Q + B*C)
#define OFF_SCORES (OFF_QK + B*C)
#define OFF_MPART  (OFF_SCORES + B*T)
#define OFF_SPART  (OFF_MPART + B*TSPLIT)
#define OFF_PPART  (OFF_SPART + B*TSPLIT)
#define OFF_POOLED (OFF_PPART + B*TSPLIT*C)

__device__ __forceinline__ bool read_mask(const void* mask, int mode, int idx) {
    if (mode == 1) return ((const unsigned char*)mask)[idx] != 0;
    if (mode == 2) return ((const float*)mask)[idx] != 0.0f;
    return ((const int*)mask)[idx] != 0;
}

// K0: detect mask dtype. Reads only first 64KB (= bool-size of B*T mask).
__global__ void k_detect(const void* mask, int* mode_out) {
    __shared__ int s_not01, s_isf;
    int tid = threadIdx.x;
    if (tid == 0) { s_not01 = 0; s_isf = 0; }
    __syncthreads();
    const int* mi = (const int*)mask;
    int not01 = 0, isf = 0;
    for (int k = 0; k < 64; ++k) {
        int v = mi[tid + 256 * k];      // 256*64 = 16384 ints = 64KB
        if (v != 0 && v != 1) not01 = 1;
        if (v == 0x3F800000) isf = 1;
    }
    if (not01) atomicOr(&s_not01, 1);
    if (isf)   atomicOr(&s_isf, 1);
    __syncthreads();
    if (tid == 0) *mode_out = s_isf ? 2 : (s_not01 ? 1 : 0);
}

// K1: per (b, t-chunk): partial masked-sum, all-sum, mask count.
__global__ __launch_bounds__(192) void
k_pass1(const float* __restrict__ tokens, const void* mask, const int* modep,
        float* __restrict__ msum, float* __restrict__ asum, float* __restrict__ cntpart) {
    int ts = blockIdx.x, b = blockIdx.y, tid = threadIdx.x;
    int mode = *modep;
    __shared__ float s_m[TCHUNK];
    if (tid < TCHUNK)
        s_m[tid] = read_mask(mask, mode, b * T + ts * TCHUNK + tid) ? 1.f : 0.f;
    __syncthreads();
    int c = tid * 4;
    float4 ms = {0, 0, 0, 0}, as = {0, 0, 0, 0};
    const float* tb = tokens + (size_t)b * T * C;
#pragma unroll 4
    for (int r = 0; r < TCHUNK; ++r) {
        int t = ts * TCHUNK + r;
        float4 x = *(const float4*)(tb + (size_t)t * C + c);
        as.x += x.x; as.y += x.y; as.z += x.z; as.w += x.w;
        float wm = s_m[r];
        ms.x += wm * x.x; ms.y += wm * x.y; ms.z += wm * x.z; ms.w += wm * x.w;
    }
    size_t o = (size_t)(b * TSPLIT + ts) * C + c;
    *(float4*)(msum + o) = ms;
    *(float4*)(asum + o) = as;
    if (tid == 0) {
        float cnt = 0.f;
#pragma unroll
        for (int r = 0; r < TCHUNK; ++r) cnt += s_m[r];
        cntpart[b * TSPLIT + ts] = cnt;
    }
}

// K2: materialize qsal once. grid (B, 3), 256 thr: each block does 256 c's.
__global__ __launch_bounds__(256) void
k_qsal(const float* __restrict__ msum, const float* __restrict__ asum,
       const float* __restrict__ cntpart, float* __restrict__ qsal) {
    int b = blockIdx.x, seg = blockIdx.y, tid = threadIdx.x;
    float cnt = 0.f;
#pragma unroll
    for (int p = 0; p < TSPLIT; ++p) cnt += cntpart[b * TSPLIT + p];
    bool um = (cnt > 0.f);
    float scale = um ? (1.f / fmaxf(cnt, 1.f)) : (1.f / (float)T);
    const float* src = um ? msum : asum;
    int c = seg * 256 + tid;
    float a = 0.f;
#pragma unroll 8
    for (int p = 0; p < TSPLIT; ++p) a += src[(size_t)(b * TSPLIT + p) * C + c];
    qsal[b * C + c] = a * scale;
}

// K3/K7: out[b,d] = scale * dot(vin[b,:], W[d,:]) for 4 b's per block.
// grid (12, 16): 64 d-outputs x 4 batches. Weight loads reused 4x.
__global__ __launch_bounds__(256) void
k_rowdot(const float* __restrict__ vin, const float* __restrict__ W,
         float* __restrict__ vout, float scale) {
    int bx = blockIdx.x, bg = blockIdx.y, tid = threadIdx.x;
    __shared__ float4 sv[4][C / 4];
    for (int i = tid; i < 4 * (C / 4); i += 256) {
        int g = i / (C / 4), j = i % (C / 4);
        sv[g][j] = ((const float4*)(vin + (size_t)(bg * 4 + g) * C))[j];
    }
    __syncthreads();
    int d = bx * 64 + (tid >> 2), sub = tid & 3;
    const float4* w = (const float4*)(W + (size_t)d * C);
    float a0 = 0.f, a1 = 0.f, a2 = 0.f, a3 = 0.f;
#pragma unroll 8
    for (int j = sub * 48; j < sub * 48 + 48; ++j) {
        float4 x = w[j];
        float4 v0 = sv[0][j], v1 = sv[1][j], v2 = sv[2][j], v3 = sv[3][j];
        a0 += x.x * v0.x + x.y * v0.y + x.z * v0.z + x.w * v0.w;
        a1 += x.x * v1.x + x.y * v1.y + x.z * v1.z + x.w * v1.w;
        a2 += x.x * v2.x + x.y * v2.y + x.z * v2.z + x.w * v2.w;
        a3 += x.x * v3.x + x.y * v3.y + x.z * v3.z + x.w * v3.w;
    }
    a0 += __shfl_xor(a0, 1); a0 += __shfl_xor(a0, 2);
    a1 += __shfl_xor(a1, 1); a1 += __shfl_xor(a1, 2);
    a2 += __shfl_xor(a2, 1); a2 += __shfl_xor(a2, 2);
    a3 += __shfl_xor(a3, 1); a3 += __shfl_xor(a3, 2);
    if (sub == 0) {
        vout[(size_t)(bg * 4 + 0) * C + d] = a0 * scale;
        vout[(size_t)(bg * 4 + 1) * C + d] = a1 * scale;
        vout[(size_t)(bg * 4 + 2) * C + d] = a2 * scale;
        vout[(size_t)(bg * 4 + 3) * C + d] = a3 * scale;
    }
}

// K4: qk[b,c] = (1/sqrt(C)) * sum_d Q[b,d] * Wk[d,c] for 4 b's per block.
__global__ __launch_bounds__(256) void
k_coldot(const float* __restrict__ Qv, const float* __restrict__ Wk,
         float* __restrict__ qk) {
    int bx = blockIdx.x, bg = blockIdx.y, tid = threadIdx.x;
    __shared__ float sQ[4][C];
    for (int i = tid; i < 4 * C; i += 256)
        sQ[i / C][i % C] = Qv[(size_t)(bg * 4 + i / C) * C + i % C];
    __syncthreads();
    int c = bx * 64 + (tid >> 2), sub = tid & 3;
    float a0 = 0.f, a1 = 0.f, a2 = 0.f, a3 = 0.f;
#pragma unroll 8
    for (int i = 0; i < 192; ++i) {
        int d = sub * 192 + i;
        float w = Wk[(size_t)d * C + c];
        a0 += sQ[0][d] * w; a1 += sQ[1][d] * w;
        a2 += sQ[2][d] * w; a3 += sQ[3][d] * w;
    }
    a0 += __shfl_xor(a0, 1); a0 += __shfl_xor(a0, 2);
    a1 += __shfl_xor(a1, 1); a1 += __shfl_xor(a1, 2);
    a2 += __shfl_xor(a2, 1); a2 += __shfl_xor(a2, 2);
    a3 += __shfl_xor(a3, 1); a3 += __shfl_xor(a3, 2);
    const float rsc = 0.03608439182435161f; // 1/sqrt(768)
    if (sub == 0) {
        qk[(size_t)(bg * 4 + 0) * C + c] = a0 * rsc;
        qk[(size_t)(bg * 4 + 1) * C + c] = a1 * rsc;
        qk[(size_t)(bg * 4 + 2) * C + c] = a2 * rsc;
        qk[(size_t)(bg * 4 + 3) * C + c] = a3 * rsc;
    }
}

// K5: fused scores + chunk softmax partials + chunk weighted pool.
__global__ __launch_bounds__(192) void
k_fused(const float* __restrict__ tokens, const float* __restrict__ qk,
        float* __restrict__ scores, float* __restrict__ mpart,
        float* __restrict__ spart, float* __restrict__ ppart) {
    __shared__ float sq[C];
    __shared__ float ssc[TCHUNK];
    __shared__ float sw[TCHUNK];
    int ts = blockIdx.x, b = blockIdx.y, tid = threadIdx.x;
    ((float4*)sq)[tid] = ((const float4*)(qk + (size_t)b * C))[tid];
    __syncthreads();
    int wave = tid >> 6, lane = tid & 63;
    const float* tb = tokens + (size_t)b * T * C;
    const float4* q4 = (const float4*)sq;
    for (int r = wave; r < TCHUNK; r += 3) {
        int t = ts * TCHUNK + r;
        const float4* row = (const float4*)(tb + (size_t)t * C);
        float acc = 0.f;
#pragma unroll
        for (int j = 0; j < 3; ++j) {
            int idx = lane + 64 * j;   // 192 float4 = 768 floats
            float4 x = row[idx], q = q4[idx];
            acc += x.x * q.x + x.y * q.y + x.z * q.z + x.w * q.w;
        }
        for (int s = 32; s > 0; s >>= 1) acc += __shfl_xor(acc, s);
        if (lane == 0) { ssc[r] = acc; scores[(size_t)b * T + t] = acc; }
    }
    __syncthreads();
    float m = -3.4e38f;
#pragma unroll
    for (int r = 0; r < TCHUNK; ++r) m = fmaxf(m, ssc[r]);
    if (tid < TCHUNK) sw[tid] = expf(ssc[tid] - m);
    __syncthreads();
    float s = 0.f;
#pragma unroll
    for (int r = 0; r < TCHUNK; ++r) s += sw[r];
    int c = tid * 4;
    float4 acc = {0, 0, 0, 0};
#pragma unroll 4
    for (int r = 0; r < TCHUNK; ++r) {
        int t = ts * TCHUNK + r;
        float wv = sw[r];
        float4 x = *(const float4*)(tb + (size_t)t * C + c);
        acc.x += wv * x.x; acc.y += wv * x.y; acc.z += wv * x.z; acc.w += wv * x.w;
    }
    *(float4*)(ppart + (size_t)(b * TSPLIT + ts) * C + c) = acc;
    if (tid == 0) { mpart[b * TSPLIT + ts] = m; spart[b * TSPLIT + ts] = s; }
}

// K6: pooled (once per b) + attn. grid (4, B): bx 0-2 -> pooled 256 c's each,
// bx 3 -> attn (256 float4 = T).
__global__ __launch_bounds__(256) void
k_pool_attn(const float* __restrict__ ppart, const float* __restrict__ scores,
            const float* __restrict__ mpart, const float* __restrict__ spart,
            float* __restrict__ pooled, float* __restrict__ attn) {
    int bx = blockIdx.x, b = blockIdx.y, tid = threadIdx.x;
    float M = -3.4e38f;
#pragma unroll
    for (int p = 0; p < TSPLIT; ++p) M = fmaxf(M, mpart[b * TSPLIT + p]);
    float Z = 0.f;
#pragma unroll
    for (int p = 0; p < TSPLIT; ++p) Z += spart[b * TSPLIT + p] * expf(mpart[b * TSPLIT + p] - M);
    float invZ = 1.f / Z;
    if (bx < 3) {
        int c = bx * 256 + tid;
        float a = 0.f;
#pragma unroll 8
        for (int p = 0; p < TSPLIT; ++p)
            a += expf(mpart[b * TSPLIT + p] - M) * invZ * ppart[(size_t)(b * TSPLIT + p) * C + c];
        pooled[b * C + c] = a;
    } else {
        float4 sc = ((const float4*)(scores + (size_t)b * T))[tid];
        float4 o;
        o.x = expf(sc.x - M) * invZ; o.y = expf(sc.y - M) * invZ;
        o.z = expf(sc.z - M) * invZ; o.w = expf(sc.w - M) * invZ;
        ((float4*)(attn + (size_t)b * T))[tid] = o;
    }
}

extern "C" void kernel_launch(void* const* d_in, const int* in_sizes, int n_in,
                              void* d_out, int out_size, void* d_ws, size_t ws_size,
                              hipStream_t stream) {
    const float* tokens = (const float*)d_in[0];
    const void*  mask   = d_in[1];
    const float* Wq     = (const float*)d_in[2];
    const float* Wk     = (const float*)d_in[3];
    const float* Wv     = (const float*)d_in[4];

    float* ws      = (float*)d_ws;
    int*   mode    = (int*)d_ws;
    float* msum    = ws + OFF_MSUM;
    float* asum    = ws + OFF_ASUM;
    float* cntpart = ws + OFF_CNT;
    float* qsal    = ws + OFF_QSAL;
    float* Qv      = ws + OFF_Q;
    float* qk      = ws + OFF_QK;
    float* scores  = ws + OFF_SCORES;
    float* mpart   = ws + OFF_MPART;
    float* spart   = ws + OFF_SPART;
    float* ppart   = ws + OFF_PPART;
    float* pooled  = ws + OFF_POOLED;

    float* v_fg = (float*)d_out;            // [B][C]
    float* attn = (float*)d_out + B * C;    // [B][T]

    k_detect<<<1, 256, 0, stream>>>(mask, mode);
    k_pass1<<<dim3(TSPLIT, B), 192, 0, stream>>>(tokens, mask, mode, msum, asum, cntpart);
    k_qsal<<<dim3(B, 3), 256, 0, stream>>>(msum, asum, cntpart, qsal);
    k_rowdot<<<dim3(12, 16), 256, 0, stream>>>(qsal, Wq, Qv, 1.0f);
    k_coldot<<<dim3(12, 16), 256, 0, stream>>>(Qv, Wk, qk);
    k_fused<<<dim3(TSPLIT, B), 192, 0, stream>>>(tokens, qk, scores, mpart, spart, ppart);
    k_pool_attn<<<dim3(4, B), 256, 0, stream>>>(ppart, scores, mpart, spart, pooled, attn);
    k_rowdot<<<dim3(12, 16), 256, 0, stream>>>(pooled, Wv, v_fg, 1.0f);
}

// Round 5
// 174.067 us; speedup vs baseline: 1.0772x; 1.0772x over previous
//
#include <hip/hip_runtime.h>
#include <hip/hip_bf16.h>

#define B 64
#define T 1024
#define C 768
#define TSPLIT 32           // t-chunks for partial reductions
#define TCHUNK (T / TSPLIT) // 32

// ---------------- ws layout (float offsets) ----------------
#define OFF_MSUM   64
#define OFF_ASUM   (OFF_MSUM + B*TSPLIT*C)
#define OFF_CNT    (OFF_ASUM + B*TSPLIT*C)
#define OFF_Q      (OFF_CNT + B*TSPLIT)
#define OFF_QK     (OFF_Q + B*C)
#define OFF_SCORES (OFF_QK + B*C)
#define OFF_MPART  (OFF_SCORES + B*T)
#define OFF_SPART  (OFF_MPART + B*TSPLIT)
#define OFF_PPART  (OFF_SPART + B*TSPLIT)

__device__ __forceinline__ bool read_mask(const void* mask, int mode, int idx) {
    if (mode == 1) return ((const unsigned char*)mask)[idx] != 0;
    if (mode == 2) return ((const float*)mask)[idx] != 0.0f;
    return ((const int*)mask)[idx] != 0;
}

// K0: detect mask dtype. Reads only first 64KB (= bool-size of B*T mask).
__global__ void k_detect(const void* mask, int* mode_out) {
    __shared__ int s_not01, s_isf;
    int tid = threadIdx.x;
    if (tid == 0) { s_not01 = 0; s_isf = 0; }
    __syncthreads();
    const int* mi = (const int*)mask;
    int not01 = 0, isf = 0;
    for (int k = 0; k < 64; ++k) {
        int v = mi[tid + 256 * k];      // 256*64 = 16384 ints = 64KB
        if (v != 0 && v != 1) not01 = 1;
        if (v == 0x3F800000) isf = 1;
    }
    if (not01) atomicOr(&s_not01, 1);
    if (isf)   atomicOr(&s_isf, 1);
    __syncthreads();
    if (tid == 0) *mode_out = s_isf ? 2 : (s_not01 ? 1 : 0);
}

// K1: per (b, t-chunk): partial masked-sum, all-sum, mask count.
__global__ __launch_bounds__(192) void
k_pass1(const float* __restrict__ tokens, const void* mask, const int* modep,
        float* __restrict__ msum, float* __restrict__ asum, float* __restrict__ cntpart) {
    int ts = blockIdx.x, b = blockIdx.y, tid = threadIdx.x;
    int mode = *modep;
    __shared__ float s_m[TCHUNK];
    if (tid < TCHUNK)
        s_m[tid] = read_mask(mask, mode, b * T + ts * TCHUNK + tid) ? 1.f : 0.f;
    __syncthreads();
    int c = tid * 4;
    float4 ms = {0, 0, 0, 0}, as = {0, 0, 0, 0};
    const float* tb = tokens + (size_t)b * T * C;
#pragma unroll 4
    for (int r = 0; r < TCHUNK; ++r) {
        int t = ts * TCHUNK + r;
        float4 x = *(const float4*)(tb + (size_t)t * C + c);
        as.x += x.x; as.y += x.y; as.z += x.z; as.w += x.w;
        float wm = s_m[r];
        ms.x += wm * x.x; ms.y += wm * x.y; ms.z += wm * x.z; ms.w += wm * x.w;
    }
    size_t o = (size_t)(b * TSPLIT + ts) * C + c;
    *(float4*)(msum + o) = ms;
    *(float4*)(asum + o) = as;
    if (tid == 0) {
        float cnt = 0.f;
#pragma unroll
        for (int r = 0; r < TCHUNK; ++r) cnt += s_m[r];
        cntpart[b * TSPLIT + ts] = cnt;
    }
}

// K2: per block (12 per b): reduce partials -> qsal (LDS), then 64 Q outputs.
__global__ __launch_bounds__(256) void
k_qsal_rowdot(const float* __restrict__ msum, const float* __restrict__ asum,
              const float* __restrict__ cntpart, const float* __restrict__ Wq,
              float* __restrict__ Qv) {
    int b = blockIdx.y, tid = threadIdx.x;
    __shared__ float sq[C];
    float cnt = 0.f;
#pragma unroll
    for (int p = 0; p < TSPLIT; ++p) cnt += cntpart[b * TSPLIT + p];
    bool um = (cnt > 0.f);
    float scale = um ? (1.f / fmaxf(cnt, 1.f)) : (1.f / (float)T);
    const float* src = um ? msum : asum;
    for (int c = tid; c < C; c += 256) {
        float a = 0.f;
#pragma unroll 8
        for (int p = 0; p < TSPLIT; ++p) a += src[(size_t)(b * TSPLIT + p) * C + c];
        sq[c] = a * scale;
    }
    __syncthreads();
    int d = blockIdx.x * 64 + (tid >> 2), sub = tid & 3;
    const float4* w = (const float4*)(Wq + (size_t)d * C);
    const float4* v4 = (const float4*)sq;
    float acc = 0.f;
#pragma unroll 8
    for (int j = sub * 48; j < sub * 48 + 48; ++j) {
        float4 a = v4[j], x = w[j];
        acc += a.x * x.x + a.y * x.y + a.z * x.z + a.w * x.w;
    }
    acc += __shfl_xor(acc, 1);
    acc += __shfl_xor(acc, 2);
    if (sub == 0) Qv[b * C + d] = acc;
}

// K3: qk[b,c] = (1/sqrt(C)) * sum_d Q[b,d] * Wk[d,c]. Q staged in LDS.
__global__ __launch_bounds__(256) void
k_coldot(const float* __restrict__ Qv, const float* __restrict__ Wk,
         float* __restrict__ qk) {
    int b = blockIdx.y, tid = threadIdx.x;
    __shared__ float sQ[C];
    for (int c = tid; c < C; c += 256) sQ[c] = Qv[b * C + c];
    __syncthreads();
    int c = blockIdx.x * 64 + (tid >> 2), sub = tid & 3;
    float acc = 0.f;
#pragma unroll 8
    for (int i = 0; i < 192; ++i) {
        int d = sub * 192 + i;
        acc += sQ[d] * Wk[(size_t)d * C + c];
    }
    acc += __shfl_xor(acc, 1);
    acc += __shfl_xor(acc, 2);
    if (sub == 0) qk[b * C + c] = acc * 0.03608439182435161f; // 1/sqrt(768)
}

// K4: fused scores + chunk softmax partials + chunk weighted pool.
__global__ __launch_bounds__(192) void
k_fused(const float* __restrict__ tokens, const float* __restrict__ qk,
        float* __restrict__ scores, float* __restrict__ mpart,
        float* __restrict__ spart, float* __restrict__ ppart) {
    __shared__ float sq[C];
    __shared__ float ssc[TCHUNK];
    __shared__ float sw[TCHUNK];
    int ts = blockIdx.x, b = blockIdx.y, tid = threadIdx.x;
    ((float4*)sq)[tid] = ((const float4*)(qk + (size_t)b * C))[tid];
    __syncthreads();
    int wave = tid >> 6, lane = tid & 63;
    const float* tb = tokens + (size_t)b * T * C;
    const float4* q4 = (const float4*)sq;
    for (int r = wave; r < TCHUNK; r += 3) {
        int t = ts * TCHUNK + r;
        const float4* row = (const float4*)(tb + (size_t)t * C);
        float acc = 0.f;
#pragma unroll
        for (int j = 0; j < 3; ++j) {
            int idx = lane + 64 * j;   // 192 float4 = 768 floats
            float4 x = row[idx], q = q4[idx];
            acc += x.x * q.x + x.y * q.y + x.z * q.z + x.w * q.w;
        }
        for (int s = 32; s > 0; s >>= 1) acc += __shfl_xor(acc, s);
        if (lane == 0) { ssc[r] = acc; scores[(size_t)b * T + t] = acc; }
    }
    __syncthreads();
    float m = -3.4e38f;
#pragma unroll
    for (int r = 0; r < TCHUNK; ++r) m = fmaxf(m, ssc[r]);
    if (tid < TCHUNK) sw[tid] = expf(ssc[tid] - m);
    __syncthreads();
    float s = 0.f;
#pragma unroll
    for (int r = 0; r < TCHUNK; ++r) s += sw[r];
    int c = tid * 4;
    float4 acc = {0, 0, 0, 0};
#pragma unroll 4
    for (int r = 0; r < TCHUNK; ++r) {
        int t = ts * TCHUNK + r;
        float wv = sw[r];
        float4 x = *(const float4*)(tb + (size_t)t * C + c);
        acc.x += wv * x.x; acc.y += wv * x.y; acc.z += wv * x.z; acc.w += wv * x.w;
    }
    *(float4*)(ppart + (size_t)(b * TSPLIT + ts) * C + c) = acc;
    if (tid == 0) { mpart[b * TSPLIT + ts] = m; spart[b * TSPLIT + ts] = s; }
}

// K5: grid (13, B). bx<12: recompute coef, build pooled in LDS, 64 v_fg outputs.
//     bx==12: write attn row (softmax of scores) — runs parallel with the GEMV.
__global__ __launch_bounds__(256) void
k_vfg_attn(const float* __restrict__ ppart, const float* __restrict__ scores,
           const float* __restrict__ mpart, const float* __restrict__ spart,
           const float* __restrict__ Wv, float* __restrict__ vfg,
           float* __restrict__ attn) {
    int bx = blockIdx.x, b = blockIdx.y, tid = threadIdx.x;
    float M = -3.4e38f;
#pragma unroll
    for (int p = 0; p < TSPLIT; ++p) M = fmaxf(M, mpart[b * TSPLIT + p]);
    float Z = 0.f;
#pragma unroll
    for (int p = 0; p < TSPLIT; ++p) Z += spart[b * TSPLIT + p] * expf(mpart[b * TSPLIT + p] - M);
    float invZ = 1.f / Z;
    if (bx == 12) {
        float4 sc = ((const float4*)(scores + (size_t)b * T))[tid];
        float4 o;
        o.x = expf(sc.x - M) * invZ; o.y = expf(sc.y - M) * invZ;
        o.z = expf(sc.z - M) * invZ; o.w = expf(sc.w - M) * invZ;
        ((float4*)(attn + (size_t)b * T))[tid] = o;
        return;
    }
    __shared__ float sp[C];
    float coef[TSPLIT];
#pragma unroll
    for (int p = 0; p < TSPLIT; ++p) coef[p] = expf(mpart[b * TSPLIT + p] - M) * invZ;
    for (int c = tid; c < C; c += 256) {
        float a = 0.f;
#pragma unroll 8
        for (int p = 0; p < TSPLIT; ++p)
            a += coef[p] * ppart[(size_t)(b * TSPLIT + p) * C + c];
        sp[c] = a;
    }
    __syncthreads();
    int d = bx * 64 + (tid >> 2), sub = tid & 3;
    const float4* w = (const float4*)(Wv + (size_t)d * C);
    const float4* v4 = (const float4*)sp;
    float acc = 0.f;
#pragma unroll 8
    for (int j = sub * 48; j < sub * 48 + 48; ++j) {
        float4 a = v4[j], x = w[j];
        acc += a.x * x.x + a.y * x.y + a.z * x.z + a.w * x.w;
    }
    acc += __shfl_xor(acc, 1);
    acc += __shfl_xor(acc, 2);
    if (sub == 0) vfg[b * C + d] = acc;
}

extern "C" void kernel_launch(void* const* d_in, const int* in_sizes, int n_in,
                              void* d_out, int out_size, void* d_ws, size_t ws_size,
                              hipStream_t stream) {
    const float* tokens = (const float*)d_in[0];
    const void*  mask   = d_in[1];
    const float* Wq     = (const float*)d_in[2];
    const float* Wk     = (const float*)d_in[3];
    const float* Wv     = (const float*)d_in[4];

    float* ws      = (float*)d_ws;
    int*   mode    = (int*)d_ws;
    float* msum    = ws + OFF_MSUM;
    float* asum    = ws + OFF_ASUM;
    float* cntpart = ws + OFF_CNT;
    float* Qv      = ws + OFF_Q;
    float* qk      = ws + OFF_QK;
    float* scores  = ws + OFF_SCORES;
    float* mpart   = ws + OFF_MPART;
    float* spart   = ws + OFF_SPART;
    float* ppart   = ws + OFF_PPART;

    float* v_fg = (float*)d_out;            // [B][C]
    float* attn = (float*)d_out + B * C;    // [B][T]

    k_detect<<<1, 256, 0, stream>>>(mask, mode);
    k_pass1<<<dim3(TSPLIT, B), 192, 0, stream>>>(tokens, mask, mode, msum, asum, cntpart);
    k_qsal_rowdot<<<dim3(12, B), 256, 0, stream>>>(msum, asum, cntpart, Wq, Qv);
    k_coldot<<<dim3(12, B), 256, 0, stream>>>(Qv, Wk, qk);
    k_fused<<<dim3(TSPLIT, B), 192, 0, stream>>>(tokens, qk, scores, mpart, spart, ppart);
    k_vfg_attn<<<dim3(13, B), 256, 0, stream>>>(ppart, scores, mpart, spart, Wv, v_fg, attn);
}

// Round 6
// 172.459 us; speedup vs baseline: 1.0872x; 1.0093x over previous
//
#include <hip/hip_runtime.h>
#include <hip/hip_bf16.h>

#define B 64
#define T 1024
#define C 768
#define TSPLIT 32           // t-chunks for partial reductions
#define TCHUNK (T / TSPLIT) // 32

// ---------------- ws layout (float offsets) ----------------
#define OFF_MSUM   64
#define OFF_CNT    (OFF_MSUM + B*TSPLIT*C)
#define OFF_Q      (OFF_CNT + B*TSPLIT)
#define OFF_QK     (OFF_Q + B*C)
#define OFF_SCORES (OFF_QK + B*C)
#define OFF_MPART  (OFF_SCORES + B*T)
#define OFF_SPART  (OFF_MPART + B*TSPLIT)
#define OFF_PPART  (OFF_SPART + B*TSPLIT)

__device__ __forceinline__ bool read_mask(const void* mask, int mode, int idx) {
    if (mode == 1) return ((const unsigned char*)mask)[idx] != 0;
    if (mode == 2) return ((const float*)mask)[idx] != 0.0f;
    return ((const int*)mask)[idx] != 0;
}

// K0: detect mask dtype. Scans first 16KB (4096 ints) — statistically conclusive.
__global__ void k_detect(const void* mask, int* mode_out) {
    __shared__ int s_not01, s_isf;
    int tid = threadIdx.x;
    if (tid == 0) { s_not01 = 0; s_isf = 0; }
    __syncthreads();
    const int* mi = (const int*)mask;
    int not01 = 0, isf = 0;
#pragma unroll
    for (int k = 0; k < 16; ++k) {
        int v = mi[tid + 256 * k];      // 256*16 = 4096 ints = 16KB
        if (v != 0 && v != 1) not01 = 1;
        if (v == 0x3F800000) isf = 1;
    }
    if (not01) atomicOr(&s_not01, 1);
    if (isf)   atomicOr(&s_isf, 1);
    __syncthreads();
    if (tid == 0) *mode_out = s_isf ? 2 : (s_not01 ? 1 : 0);
}

// K1: per (b, t-chunk): partial masked-sum + mask count. (all-sum dropped —
// mean_all fallback handled by cold path in K2.)
__global__ __launch_bounds__(192) void
k_pass1(const float* __restrict__ tokens, const void* mask, const int* modep,
        float* __restrict__ msum, float* __restrict__ cntpart) {
    int ts = blockIdx.x, b = blockIdx.y, tid = threadIdx.x;
    int mode = *modep;
    __shared__ float s_m[TCHUNK];
    if (tid < TCHUNK)
        s_m[tid] = read_mask(mask, mode, b * T + ts * TCHUNK + tid) ? 1.f : 0.f;
    __syncthreads();
    int c = tid * 4;
    float4 ms = {0, 0, 0, 0};
    const float* tb = tokens + (size_t)b * T * C;
#pragma unroll 4
    for (int r = 0; r < TCHUNK; ++r) {
        int t = ts * TCHUNK + r;
        float4 x = *(const float4*)(tb + (size_t)t * C + c);
        float wm = s_m[r];
        ms.x += wm * x.x; ms.y += wm * x.y; ms.z += wm * x.z; ms.w += wm * x.w;
    }
    *(float4*)(msum + (size_t)(b * TSPLIT + ts) * C + c) = ms;
    if (tid == 0) {
        float cnt = 0.f;
#pragma unroll
        for (int r = 0; r < TCHUNK; ++r) cnt += s_m[r];
        cntpart[b * TSPLIT + ts] = cnt;
    }
}

// K2: per block (12 per b): reduce partials -> qsal (LDS), then 64 Q outputs.
// Cold path (cnt==0, never taken with this dataset): mean over all tokens.
__global__ __launch_bounds__(256) void
k_qsal_rowdot(const float* __restrict__ msum, const float* __restrict__ cntpart,
              const float* __restrict__ tokens, const float* __restrict__ Wq,
              float* __restrict__ Qv) {
    int b = blockIdx.y, tid = threadIdx.x;
    __shared__ float sq[C];
    float cnt = 0.f;
#pragma unroll
    for (int p = 0; p < TSPLIT; ++p) cnt += cntpart[b * TSPLIT + p];
    if (cnt > 0.f) {
        float scale = 1.f / cnt;   // cnt >= 1 when > 0
        for (int c = tid; c < C; c += 256) {
            float a = 0.f;
#pragma unroll 8
            for (int p = 0; p < TSPLIT; ++p) a += msum[(size_t)(b * TSPLIT + p) * C + c];
            sq[c] = a * scale;
        }
    } else {
        const float* tb = tokens + (size_t)b * T * C;
        for (int c = tid; c < C; c += 256) {
            float a = 0.f;
            for (int t = 0; t < T; ++t) a += tb[(size_t)t * C + c];
            sq[c] = a * (1.f / (float)T);
        }
    }
    __syncthreads();
    int d = blockIdx.x * 64 + (tid >> 2), sub = tid & 3;
    const float4* w = (const float4*)(Wq + (size_t)d * C);
    const float4* v4 = (const float4*)sq;
    float acc = 0.f;
#pragma unroll 8
    for (int j = sub * 48; j < sub * 48 + 48; ++j) {
        float4 a = v4[j], x = w[j];
        acc += a.x * x.x + a.y * x.y + a.z * x.z + a.w * x.w;
    }
    acc += __shfl_xor(acc, 1);
    acc += __shfl_xor(acc, 2);
    if (sub == 0) Qv[b * C + d] = acc;
}

// K3: qk[b,c] = (1/sqrt(C)) * sum_d Q[b,d] * Wk[d,c]. Q staged in LDS.
__global__ __launch_bounds__(256) void
k_coldot(const float* __restrict__ Qv, const float* __restrict__ Wk,
         float* __restrict__ qk) {
    int b = blockIdx.y, tid = threadIdx.x;
    __shared__ float sQ[C];
    for (int c = tid; c < C; c += 256) sQ[c] = Qv[b * C + c];
    __syncthreads();
    int c = blockIdx.x * 64 + (tid >> 2), sub = tid & 3;
    float acc = 0.f;
#pragma unroll 8
    for (int i = 0; i < 192; ++i) {
        int d = sub * 192 + i;
        acc += sQ[d] * Wk[(size_t)d * C + c];
    }
    acc += __shfl_xor(acc, 1);
    acc += __shfl_xor(acc, 2);
    if (sub == 0) qk[b * C + c] = acc * 0.03608439182435161f; // 1/sqrt(768)
}

// K4: fused scores + chunk softmax partials + chunk weighted pool. 256 thr:
// score loop = 4 waves x 8 rows; pool phase = 192-lane float4 mapping.
__global__ __launch_bounds__(256) void
k_fused(const float* __restrict__ tokens, const float* __restrict__ qk,
        float* __restrict__ scores, float* __restrict__ mpart,
        float* __restrict__ spart, float* __restrict__ ppart) {
    __shared__ float sq[C];
    __shared__ float ssc[TCHUNK];
    __shared__ float sw[TCHUNK];
    int ts = blockIdx.x, b = blockIdx.y, tid = threadIdx.x;
    if (tid < 192) ((float4*)sq)[tid] = ((const float4*)(qk + (size_t)b * C))[tid];
    __syncthreads();
    int wave = tid >> 6, lane = tid & 63;
    const float* tb = tokens + (size_t)b * T * C;
    const float4* q4 = (const float4*)sq;
#pragma unroll
    for (int rr = 0; rr < TCHUNK / 4; ++rr) {
        int r = rr * 4 + wave;
        int t = ts * TCHUNK + r;
        const float4* row = (const float4*)(tb + (size_t)t * C);
        float acc = 0.f;
#pragma unroll
        for (int j = 0; j < 3; ++j) {
            int idx = lane + 64 * j;   // 192 float4 = 768 floats
            float4 x = row[idx], q = q4[idx];
            acc += x.x * q.x + x.y * q.y + x.z * q.z + x.w * q.w;
        }
        for (int s = 32; s > 0; s >>= 1) acc += __shfl_xor(acc, s);
        if (lane == 0) { ssc[r] = acc; scores[(size_t)b * T + t] = acc; }
    }
    __syncthreads();
    float m = -3.4e38f;
#pragma unroll
    for (int r = 0; r < TCHUNK; ++r) m = fmaxf(m, ssc[r]);
    if (tid < TCHUNK) sw[tid] = expf(ssc[tid] - m);
    __syncthreads();
    if (tid < 192) {
        int c = tid * 4;
        float4 acc = {0, 0, 0, 0};
#pragma unroll 4
        for (int r = 0; r < TCHUNK; ++r) {
            int t = ts * TCHUNK + r;
            float wv = sw[r];
            float4 x = *(const float4*)(tb + (size_t)t * C + c);
            acc.x += wv * x.x; acc.y += wv * x.y; acc.z += wv * x.z; acc.w += wv * x.w;
        }
        *(float4*)(ppart + (size_t)(b * TSPLIT + ts) * C + c) = acc;
    }
    if (tid == 0) {
        float s = 0.f;
#pragma unroll
        for (int r = 0; r < TCHUNK; ++r) s += sw[r];
        mpart[b * TSPLIT + ts] = m;
        spart[b * TSPLIT + ts] = s;
    }
}

// K5: grid (13, B). bx<12: recompute coef, build pooled in LDS, 64 v_fg outputs.
//     bx==12: write attn row (softmax of scores) — runs parallel with the GEMV.
__global__ __launch_bounds__(256) void
k_vfg_attn(const float* __restrict__ ppart, const float* __restrict__ scores,
           const float* __restrict__ mpart, const float* __restrict__ spart,
           const float* __restrict__ Wv, float* __restrict__ vfg,
           float* __restrict__ attn) {
    int bx = blockIdx.x, b = blockIdx.y, tid = threadIdx.x;
    float M = -3.4e38f;
#pragma unroll
    for (int p = 0; p < TSPLIT; ++p) M = fmaxf(M, mpart[b * TSPLIT + p]);
    float Z = 0.f;
#pragma unroll
    for (int p = 0; p < TSPLIT; ++p) Z += spart[b * TSPLIT + p] * expf(mpart[b * TSPLIT + p] - M);
    float invZ = 1.f / Z;
    if (bx == 12) {
        float4 sc = ((const float4*)(scores + (size_t)b * T))[tid];
        float4 o;
        o.x = expf(sc.x - M) * invZ; o.y = expf(sc.y - M) * invZ;
        o.z = expf(sc.z - M) * invZ; o.w = expf(sc.w - M) * invZ;
        ((float4*)(attn + (size_t)b * T))[tid] = o;
        return;
    }
    __shared__ float sp[C];
    float coef[TSPLIT];
#pragma unroll
    for (int p = 0; p < TSPLIT; ++p) coef[p] = expf(mpart[b * TSPLIT + p] - M) * invZ;
    for (int c = tid; c < C; c += 256) {
        float a = 0.f;
#pragma unroll 8
        for (int p = 0; p < TSPLIT; ++p)
            a += coef[p] * ppart[(size_t)(b * TSPLIT + p) * C + c];
        sp[c] = a;
    }
    __syncthreads();
    int d = bx * 64 + (tid >> 2), sub = tid & 3;
    const float4* w = (const float4*)(Wv + (size_t)d * C);
    const float4* v4 = (const float4*)sp;
    float acc = 0.f;
#pragma unroll 8
    for (int j = sub * 48; j < sub * 48 + 48; ++j) {
        float4 a = v4[j], x = w[j];
        acc += a.x * x.x + a.y * x.y + a.z * x.z + a.w * x.w;
    }
    acc += __shfl_xor(acc, 1);
    acc += __shfl_xor(acc, 2);
    if (sub == 0) vfg[b * C + d] = acc;
}

extern "C" void kernel_launch(void* const* d_in, const int* in_sizes, int n_in,
                              void* d_out, int out_size, void* d_ws, size_t ws_size,
                              hipStream_t stream) {
    const float* tokens = (const float*)d_in[0];
    const void*  mask   = d_in[1];
    const float* Wq     = (const float*)d_in[2];
    const float* Wk     = (const float*)d_in[3];
    const float* Wv     = (const float*)d_in[4];

    float* ws      = (float*)d_ws;
    int*   mode    = (int*)d_ws;
    float* msum    = ws + OFF_MSUM;
    float* cntpart = ws + OFF_CNT;
    float* Qv      = ws + OFF_Q;
    float* qk      = ws + OFF_QK;
    float* scores  = ws + OFF_SCORES;
    float* mpart   = ws + OFF_MPART;
    float* spart   = ws + OFF_SPART;
    float* ppart   = ws + OFF_PPART;

    float* v_fg = (float*)d_out;            // [B][C]
    float* attn = (float*)d_out + B * C;    // [B][T]

    k_detect<<<1, 256, 0, stream>>>(mask, mode);
    k_pass1<<<dim3(TSPLIT, B), 192, 0, stream>>>(tokens, mask, mode, msum, cntpart);
    k_qsal_rowdot<<<dim3(12, B), 256, 0, stream>>>(msum, cntpart, tokens, Wq, Qv);
    k_coldot<<<dim3(12, B), 256, 0, stream>>>(Qv, Wk, qk);
    k_fused<<<dim3(TSPLIT, B), 256, 0, stream>>>(tokens, qk, scores, mpart, spart, ppart);
    k_vfg_attn<<<dim3(13, B), 256, 0, stream>>>(ppart, scores, mpart, spart, Wv, v_fg, attn);
}